// Round 9
// baseline (278.725 us; speedup 1.0000x reference)
//
#include <hip/hip_runtime.h>
#include <hip/hip_bf16.h>

#define D_MODEL 1024
#define NUM_HEADS 16
#define HEAD_DIM 64
#define BATCH 4
#define SEQ 2048
#define MROWS (BATCH * SEQ)

using f32x4  = __attribute__((ext_vector_type(4))) float;
using bf16x8 = __attribute__((ext_vector_type(8))) short;

__device__ inline unsigned short f2bf(float f) {
    __hip_bfloat16 h = __float2bfloat16(f);
    return *reinterpret_cast<unsigned short*>(&h);
}

// async global->LDS, 16B per lane; lds base must be wave-uniform
__device__ inline void gld_lds16(const unsigned short* g, unsigned short* l) {
    __builtin_amdgcn_global_load_lds(
        (const __attribute__((address_space(1))) unsigned int*)g,
        (__attribute__((address_space(3))) unsigned int*)l, 16, 0, 0);
}

#define QSCALE 0.18033688011112042f   // 0.125 / ln(2)

// ---------------------------------------------------------------------------
// prep = build_w + xcast fused into ONE launch (disjoint work, blockIdx
// partition).
//   bid <  4096 : build circulant weights, B^T layout Wt[n][k]=c[(n-k)&1023],
//                 Wq/bq pre-scaled by QSCALE (attn uses exp2 directly).
//   bid >= 4096 : cast x (f32) -> xb (bf16), 1024 elems per block.
// ---------------------------------------------------------------------------
__global__ __launch_bounds__(256) void prep(
    const float* __restrict__ cq, const float* __restrict__ ck,
    const float* __restrict__ cv, const float* __restrict__ co,
    const float* __restrict__ bq, const float* __restrict__ bk,
    const float* __restrict__ bv, const float* __restrict__ bo,
    unsigned short* __restrict__ Wt, float* __restrict__ bias,
    const float* __restrict__ x, unsigned short* __restrict__ xb)
{
    const int bid = blockIdx.x;
    const int t = threadIdx.x;
    if (bid < 4096) {
        const int n = bid;
        const int sel = n >> 10, nl = n & 1023;
        const float* c  = sel == 0 ? cq : sel == 1 ? ck : sel == 2 ? cv : co;
        const float* bb = sel == 0 ? bq : sel == 1 ? bk : sel == 2 ? bv : bo;
        const float sc = (sel == 0) ? QSCALE : 1.0f;
        ushort4 o;
        o.x = f2bf(sc * c[(nl - (4*t + 0)) & 1023]);
        o.y = f2bf(sc * c[(nl - (4*t + 1)) & 1023]);
        o.z = f2bf(sc * c[(nl - (4*t + 2)) & 1023]);
        o.w = f2bf(sc * c[(nl - (4*t + 3)) & 1023]);
        ((ushort4*)(Wt + (size_t)n * 1024))[t] = o;
        if (t == 0) bias[n] = sc * bb[nl];
    } else {
        const size_t i = (size_t)(bid - 4096) * 1024 + t * 4;
        float4 v = *(const float4*)(x + i);
        ushort4 o;
        o.x = f2bf(v.x); o.y = f2bf(v.y); o.z = f2bf(v.z); o.w = f2bf(v.w);
        *(ushort4*)(xb + i) = o;
    }
}

// ---------------------------------------------------------------------------
// bf16 GEMM: C = A * W + bias. 128x128 tile, BK=64, XOR swizzle, gld_lds16.
// (Proven m97 structure; R7's V-LDS-transpose epilogue reverted: +3.2us.)
// NEW: bijective XCD-chunked grid swizzle (T1) — each XCD gets a contiguous
// tile chunk so its B-panels stay L2-resident and the per-tile vmcnt drain
// hits L2 instead of L3. Requires nwg % 8 == 0 (1536 and 512: both OK).
// OUT_MODE 0: Q row-major; K row-major; V transposed per (b,head).
// OUT_MODE 1: fp32 out.
// ---------------------------------------------------------------------------
template <int OUT_MODE>
__global__ __launch_bounds__(256, 3) void gemm_circ(
    const unsigned short* __restrict__ A,
    const unsigned short* __restrict__ Bt,
    const float* __restrict__ bias,
    unsigned short* __restrict__ Qb, unsigned short* __restrict__ Kb,
    unsigned short* __restrict__ Vt, float* __restrict__ Cf)
{
    __shared__ unsigned short As[128 * 64];
    __shared__ unsigned short Bs[128 * 64];
    const int t = threadIdx.x;
    const int w = t >> 6, lane = t & 63;
    const int quad = lane >> 4, l16 = lane & 15;

    // XCD-chunked swizzle: dispatch round-robins flat id over 8 XCDs; remap
    // so XCD k processes contiguous tile range [k*cpx, (k+1)*cpx).
    const int flat = blockIdx.y * gridDim.x + blockIdx.x;
    const int cpx  = (gridDim.x * gridDim.y) >> 3;
    const int nf   = (flat & 7) * cpx + (flat >> 3);
    const int m0 = (nf % gridDim.x) * 128;
    const int n0 = (nf / gridDim.x) * 128;
    const int wm = (w & 1) * 64, wn = (w >> 1) * 64;

    f32x4 acc[4][4];
#pragma unroll
    for (int i = 0; i < 4; ++i)
#pragma unroll
        for (int j = 0; j < 4; ++j) acc[i][j] = (f32x4){0.f, 0.f, 0.f, 0.f};

    for (int k0 = 0; k0 < 1024; k0 += 64) {
        __syncthreads();
#pragma unroll
        for (int j = 0; j < 4; ++j) {
            const int s = j * 4 + w;
            const int i = s * 64 + lane;
            const int r = i >> 3;
            const int c = (i & 7) ^ (r & 7);
            gld_lds16(A  + (size_t)(m0 + r) * 1024 + k0 + c * 8, &As[s * 512]);
            gld_lds16(Bt + (size_t)(n0 + r) * 1024 + k0 + c * 8, &Bs[s * 512]);
        }
        __syncthreads();

#pragma unroll
        for (int kk = 0; kk < 2; ++kk) {
            bf16x8 af[4], bfr[4];
#pragma unroll
            for (int i = 0; i < 4; ++i) {
                const int r = wm + i * 16 + l16;
                const int slot = r * 8 + ((kk * 4 + quad) ^ (r & 7));
                af[i] = *(const bf16x8*)&As[slot * 8];
            }
#pragma unroll
            for (int j = 0; j < 4; ++j) {
                const int r = wn + j * 16 + l16;
                const int slot = r * 8 + ((kk * 4 + quad) ^ (r & 7));
                bfr[j] = *(const bf16x8*)&Bs[slot * 8];
            }
#pragma unroll
            for (int i = 0; i < 4; ++i)
#pragma unroll
                for (int j = 0; j < 4; ++j)
                    acc[i][j] = __builtin_amdgcn_mfma_f32_16x16x32_bf16(
                        af[i], bfr[j], acc[i][j], 0, 0, 0);
        }
    }

#pragma unroll
    for (int i = 0; i < 4; ++i) {
        const int gm = m0 + wm + i * 16 + quad * 4;
#pragma unroll
        for (int j = 0; j < 4; ++j) {
            const int gn = n0 + wn + j * 16 + l16;
            const float bv = bias[gn];
            if (OUT_MODE == 1) {
#pragma unroll
                for (int rr = 0; rr < 4; ++rr)
                    Cf[(size_t)(gm + rr) * 1024 + gn] = acc[i][j][rr] + bv;
            } else {
                const int sel = gn >> 10;
                if (sel == 0) {
#pragma unroll
                    for (int rr = 0; rr < 4; ++rr)
                        Qb[(size_t)(gm + rr) * 1024 + gn] = f2bf(acc[i][j][rr] + bv);
                } else if (sel == 1) {
                    const int col = gn & 1023;
#pragma unroll
                    for (int rr = 0; rr < 4; ++rr)
                        Kb[(size_t)(gm + rr) * 1024 + col] = f2bf(acc[i][j][rr] + bv);
                } else {
                    const int d = gn & 1023;
                    const int head = d >> 6, dl = d & 63;
                    const int b = gm >> 11, key = gm & 2047;
                    ushort4 vv;
                    vv.x = f2bf(acc[i][j][0] + bv);
                    vv.y = f2bf(acc[i][j][1] + bv);
                    vv.z = f2bf(acc[i][j][2] + bv);
                    vv.w = f2bf(acc[i][j][3] + bv);
                    *(ushort4*)&Vt[((size_t)((b * 16 + head) * 64 + dl)) * 2048 + key] = vv;
                }
            }
        }
    }
}

// ---------------------------------------------------------------------------
// MFMA attention v13 = v11 structure (in-register P via key-interleave, MFMA
// row-sum denominator, NO setprio) at 512 threads / 8 waves / 256 q per
// block. Staging is per-block, so doubling q/block HALVES total K/V staging
// traffic (16 -> 8 K/V sweeps per (b,head)) and halves each wave's gld_lds
// issue + address VALU. Occupancy unchanged: 2 blocks/CU x 8 waves = 16
// waves/CU, LDS 32KB/block. Per-wave math identical to v11.
// ---------------------------------------------------------------------------
__global__ __launch_bounds__(512, 4) void attn_mfma(
    const unsigned short* __restrict__ Qb, const unsigned short* __restrict__ Kb,
    const unsigned short* __restrict__ Vt, unsigned short* __restrict__ O)
{
    __shared__ unsigned short Ks[2][64 * 64];   // [buf][key][d] swizzled (sg)
    __shared__ unsigned short Vs[2][64 * 64];   // [buf][d][key] swizzled (r&7)

    const int t = threadIdx.x;
    const int w = t >> 6, lane = t & 63;        // w in 0..7
    const int quad = lane >> 4, l16 = lane & 15;
    const int bh = blockIdx.x;                  // fast axis: (b,head)
    const int b = bh >> 4, head = bh & 15;
    const int qbase = blockIdx.y * 256 + w * 32;

    // Q fragments (B-operand of S^T = K Q^T): lane l16 = q-col, regs = d.
    bf16x8 qa[2][2];
#pragma unroll
    for (int s = 0; s < 2; ++s)
#pragma unroll
        for (int h = 0; h < 2; ++h) {
            size_t off = (size_t)(b * SEQ + qbase + s*16 + l16) * D_MODEL
                       + head * HEAD_DIM + h*32 + quad*8;
            qa[s][h] = *(const bf16x8*)(Qb + off);
        }

    f32x4 acc[2][4];     // [strip][d-tile], C-layout row=q, col=d
    f32x4 acc_sum[2];    // row sums via MFMA(P, ones): denom(q) broadcast to all cols
#pragma unroll
    for (int s = 0; s < 2; ++s) {
#pragma unroll
        for (int dt = 0; dt < 4; ++dt) acc[s][dt] = (f32x4){0.f,0.f,0.f,0.f};
        acc_sum[s] = (f32x4){0.f,0.f,0.f,0.f};
    }

    // all-ones bf16 B-operand (1.0bf16 = 0x3F80)
    bf16x8 vones;
#pragma unroll
    for (int i = 0; i < 8; ++i) vones[i] = (short)0x3F80;

    const size_t kbase  = (size_t)(b * SEQ) * D_MODEL + head * HEAD_DIM;
    const size_t vtbase = (size_t)((b * NUM_HEADS + head) * HEAD_DIM) * SEQ;

    // staging: 8 waves cover the 8 segs of each tile (1 K + 1 V per wave)
    const int r  = t >> 3;                      // 0..63 (row of 64-row tile)
    const int ck = (t & 7) ^ ((r & 3) | ((r >> 1) & 4));
    const int cv = (t & 7) ^ (r & 7);

    // prologue: stage k-block 0 into buffer 0
    gld_lds16(Kb + kbase + (size_t)r * D_MODEL + ck * 8, &Ks[0][w * 512]);
    gld_lds16(Vt + vtbase + (size_t)r * SEQ + cv * 8, &Vs[0][w * 512]);

    int ib = 0;
    for (int kb = 0; kb < SEQ; kb += 64, ib ^= 1) {
        __syncthreads();   // buf ib staged

        if (kb + 64 < SEQ) {
            gld_lds16(Kb + kbase + (size_t)(kb + 64 + r) * D_MODEL + ck * 8,
                      &Ks[ib ^ 1][w * 512]);
            gld_lds16(Vt + vtbase + (size_t)r * SEQ + kb + 64 + cv * 8,
                      &Vs[ib ^ 1][w * 512]);
        }

        // K fragments, permuted rows (A-row a holds key kh*32+(a>>2)*8+m*4+(a&3))
        bf16x8 kf[2][2][2];   // [kh][m][h]
#pragma unroll
        for (int kh = 0; kh < 2; ++kh)
#pragma unroll
            for (int m = 0; m < 2; ++m) {
                const int rk = kh * 32 + ((l16 >> 2) << 3) + m * 4 + (l16 & 3);
                const int sg = (rk & 3) | ((rk >> 1) & 4);
#pragma unroll
                for (int h = 0; h < 2; ++h) {
                    const int cc = (h * 4 + quad) ^ sg;
                    kf[kh][m][h] = *(const bf16x8*)&Ks[ib][(rk * 8 + cc) * 8];
                }
            }

#pragma unroll
        for (int kh = 0; kh < 2; ++kh) {
            // S^T = K Q^T with interleaved key rows; exp2; pack -> in-reg pf
            bf16x8 pf[2];
#pragma unroll
            for (int s = 0; s < 2; ++s) {
                f32x4 st0 = (f32x4){0.f,0.f,0.f,0.f};
                f32x4 st1 = (f32x4){0.f,0.f,0.f,0.f};
#pragma unroll
                for (int h = 0; h < 2; ++h) {
                    st0 = __builtin_amdgcn_mfma_f32_16x16x32_bf16(
                        kf[kh][0][h], qa[s][h], st0, 0, 0, 0);
                    st1 = __builtin_amdgcn_mfma_f32_16x16x32_bf16(
                        kf[kh][1][h], qa[s][h], st1, 0, 0, 0);
                }
                // lane holds keys kh*32 + quad*8 + {0..7} for q = s*16+l16
                float p0 = __builtin_amdgcn_exp2f(st0[0]);
                float p1 = __builtin_amdgcn_exp2f(st0[1]);
                float p2 = __builtin_amdgcn_exp2f(st0[2]);
                float p3 = __builtin_amdgcn_exp2f(st0[3]);
                float p4 = __builtin_amdgcn_exp2f(st1[0]);
                float p5 = __builtin_amdgcn_exp2f(st1[1]);
                float p6 = __builtin_amdgcn_exp2f(st1[2]);
                float p7 = __builtin_amdgcn_exp2f(st1[3]);
                __hip_bfloat162 w0 = __float22bfloat162_rn(make_float2(p0, p1));
                __hip_bfloat162 w1 = __float22bfloat162_rn(make_float2(p2, p3));
                __hip_bfloat162 w2 = __float22bfloat162_rn(make_float2(p4, p5));
                __hip_bfloat162 w3 = __float22bfloat162_rn(make_float2(p6, p7));
                union { bf16x8 v; unsigned int u[4]; } pu;
                pu.u[0] = *reinterpret_cast<unsigned int*>(&w0);
                pu.u[1] = *reinterpret_cast<unsigned int*>(&w1);
                pu.u[2] = *reinterpret_cast<unsigned int*>(&w2);
                pu.u[3] = *reinterpret_cast<unsigned int*>(&w3);
                pf[s] = pu.v;
            }

            // O += P V (pf in-register, vf from LDS); row-sum via MFMA(P, 1)
#pragma unroll
            for (int dt = 0; dt < 4; ++dt) {
                const int rv = dt * 16 + l16;
                const int cvv = (kh * 4 + quad) ^ (rv & 7);
                bf16x8 vf = *(const bf16x8*)&Vs[ib][(rv * 8 + cvv) * 8];
#pragma unroll
                for (int s = 0; s < 2; ++s)
                    acc[s][dt] = __builtin_amdgcn_mfma_f32_16x16x32_bf16(
                        pf[s], vf, acc[s][dt], 0, 0, 0);
            }
#pragma unroll
            for (int s = 0; s < 2; ++s)
                acc_sum[s] = __builtin_amdgcn_mfma_f32_16x16x32_bf16(
                    pf[s], vones, acc_sum[s], 0, 0, 0);
        }
    }

    // epilogue: denom(q = s*16+quad*4+rr) is in acc_sum[s][rr] of every lane
#pragma unroll
    for (int s = 0; s < 2; ++s)
#pragma unroll
        for (int rr = 0; rr < 4; ++rr) {
            float inv = 1.0f / acc_sum[s][rr];
            int q = qbase + s*16 + quad*4 + rr;
            unsigned short* orow = O + (size_t)(b * SEQ + q) * D_MODEL + head * HEAD_DIM + l16;
#pragma unroll
            for (int dt = 0; dt < 4; ++dt) orow[dt*16] = f2bf(acc[s][dt][rr] * inv);
        }
}

extern "C" void kernel_launch(void* const* d_in, const int* in_sizes, int n_in,
                              void* d_out, int out_size, void* d_ws, size_t ws_size,
                              hipStream_t stream) {
    const float* x    = (const float*)d_in[0];
    const float* wq_c = (const float*)d_in[1];
    const float* wq_b = (const float*)d_in[2];
    const float* wk_c = (const float*)d_in[3];
    const float* wk_b = (const float*)d_in[4];
    const float* wv_c = (const float*)d_in[5];
    const float* wv_b = (const float*)d_in[6];
    const float* wo_c = (const float*)d_in[7];
    const float* wo_b = (const float*)d_in[8];
    float* out = (float*)d_out;

    char* ws = (char*)d_ws;
    unsigned short* Wt   = (unsigned short*)(ws);                        // 8 MB
    float*          bias = (float*)(ws + ((size_t)8  << 20));            // 16 KB
    unsigned short* xb   = (unsigned short*)(ws + ((size_t)10 << 20));   // 16 MB
    unsigned short* Qb   = (unsigned short*)(ws + ((size_t)26 << 20));   // 16 MB
    unsigned short* Kb   = (unsigned short*)(ws + ((size_t)42 << 20));   // 16 MB
    unsigned short* Vt   = (unsigned short*)(ws + ((size_t)58 << 20));   // 16 MB
    unsigned short* Ob   = (unsigned short*)(ws + ((size_t)74 << 20));   // 16 MB

    prep<<<4096 + MROWS, 256, 0, stream>>>(wq_c, wk_c, wv_c, wo_c,
                                           wq_b, wk_b, wv_b, wo_b,
                                           Wt, bias, x, xb);
    gemm_circ<0><<<dim3(64, 24), 256, 0, stream>>>(xb, Wt, bias, Qb, Kb, Vt, nullptr);
    // fast axis = (b,head): round-robin over XCDs; q-tiles (slow) revisit warm L2
    attn_mfma<<<dim3(BATCH * NUM_HEADS, SEQ / 256), 512, 0, stream>>>(Qb, Kb, Vt, Ob);
    gemm_circ<1><<<dim3(64, 8), 256, 0, stream>>>(Ob, Wt + (size_t)3072 * 1024,
                                                  bias + 3072, nullptr, nullptr, nullptr, out);
}

// Round 10
// 245.045 us; speedup vs baseline: 1.1374x; 1.1374x over previous
//
#include <hip/hip_runtime.h>
#include <hip/hip_bf16.h>

#define D_MODEL 1024
#define NUM_HEADS 16
#define HEAD_DIM 64
#define BATCH 4
#define SEQ 2048
#define MROWS (BATCH * SEQ)

using f32x4  = __attribute__((ext_vector_type(4))) float;
using bf16x8 = __attribute__((ext_vector_type(8))) short;

__device__ inline unsigned short f2bf(float f) {
    __hip_bfloat16 h = __float2bfloat16(f);
    return *reinterpret_cast<unsigned short*>(&h);
}

// async global->LDS, 16B per lane; lds base must be wave-uniform
__device__ inline void gld_lds16(const unsigned short* g, unsigned short* l) {
    __builtin_amdgcn_global_load_lds(
        (const __attribute__((address_space(1))) unsigned int*)g,
        (__attribute__((address_space(3))) unsigned int*)l, 16, 0, 0);
}

#define QSCALE 0.18033688011112042f   // 0.125 / ln(2)

// ---------------------------------------------------------------------------
// prep = build_w + xcast fused into ONE launch (disjoint work, blockIdx
// partition).
//   bid <  4096 : build circulant weights, B^T layout Wt[n][k]=c[(n-k)&1023],
//                 Wq/bq pre-scaled by QSCALE (attn uses exp2 directly).
//   bid >= 4096 : cast x (f32) -> xb (bf16), 1024 elems per block.
// ---------------------------------------------------------------------------
__global__ __launch_bounds__(256) void prep(
    const float* __restrict__ cq, const float* __restrict__ ck,
    const float* __restrict__ cv, const float* __restrict__ co,
    const float* __restrict__ bq, const float* __restrict__ bk,
    const float* __restrict__ bv, const float* __restrict__ bo,
    unsigned short* __restrict__ Wt, float* __restrict__ bias,
    const float* __restrict__ x, unsigned short* __restrict__ xb)
{
    const int bid = blockIdx.x;
    const int t = threadIdx.x;
    if (bid < 4096) {
        const int n = bid;
        const int sel = n >> 10, nl = n & 1023;
        const float* c  = sel == 0 ? cq : sel == 1 ? ck : sel == 2 ? cv : co;
        const float* bb = sel == 0 ? bq : sel == 1 ? bk : sel == 2 ? bv : bo;
        const float sc = (sel == 0) ? QSCALE : 1.0f;
        ushort4 o;
        o.x = f2bf(sc * c[(nl - (4*t + 0)) & 1023]);
        o.y = f2bf(sc * c[(nl - (4*t + 1)) & 1023]);
        o.z = f2bf(sc * c[(nl - (4*t + 2)) & 1023]);
        o.w = f2bf(sc * c[(nl - (4*t + 3)) & 1023]);
        ((ushort4*)(Wt + (size_t)n * 1024))[t] = o;
        if (t == 0) bias[n] = sc * bb[nl];
    } else {
        const size_t i = (size_t)(bid - 4096) * 1024 + t * 4;
        float4 v = *(const float4*)(x + i);
        ushort4 o;
        o.x = f2bf(v.x); o.y = f2bf(v.y); o.z = f2bf(v.z); o.w = f2bf(v.w);
        *(ushort4*)(xb + i) = o;
    }
}

// ---------------------------------------------------------------------------
// bf16 GEMM: C = A * W + bias. 128x128 tile, BK=64, XOR swizzle, gld_lds16.
// Proven m97 structure, NATURAL dispatch order (R8's XCD-chunk swizzle
// reverted: it made each XCD's live A working set = all 16MB >> 4MB L2,
// FETCH 22->181MB, memory-bound. Natural x-fast order keeps 8 m-tiles +
// 12 B-panels per XCD ~ L2-sized).
// OUT_MODE 0: Q row-major; K row-major; V transposed per (b,head).
// OUT_MODE 1: fp32 out.
// ---------------------------------------------------------------------------
template <int OUT_MODE>
__global__ __launch_bounds__(256, 3) void gemm_circ(
    const unsigned short* __restrict__ A,
    const unsigned short* __restrict__ Bt,
    const float* __restrict__ bias,
    unsigned short* __restrict__ Qb, unsigned short* __restrict__ Kb,
    unsigned short* __restrict__ Vt, float* __restrict__ Cf)
{
    __shared__ unsigned short As[128 * 64];
    __shared__ unsigned short Bs[128 * 64];
    const int t = threadIdx.x;
    const int w = t >> 6, lane = t & 63;
    const int quad = lane >> 4, l16 = lane & 15;
    const int m0 = blockIdx.x * 128;
    const int n0 = blockIdx.y * 128;
    const int wm = (w & 1) * 64, wn = (w >> 1) * 64;

    f32x4 acc[4][4];
#pragma unroll
    for (int i = 0; i < 4; ++i)
#pragma unroll
        for (int j = 0; j < 4; ++j) acc[i][j] = (f32x4){0.f, 0.f, 0.f, 0.f};

    for (int k0 = 0; k0 < 1024; k0 += 64) {
        __syncthreads();
#pragma unroll
        for (int j = 0; j < 4; ++j) {
            const int s = j * 4 + w;
            const int i = s * 64 + lane;
            const int r = i >> 3;
            const int c = (i & 7) ^ (r & 7);
            gld_lds16(A  + (size_t)(m0 + r) * 1024 + k0 + c * 8, &As[s * 512]);
            gld_lds16(Bt + (size_t)(n0 + r) * 1024 + k0 + c * 8, &Bs[s * 512]);
        }
        __syncthreads();

#pragma unroll
        for (int kk = 0; kk < 2; ++kk) {
            bf16x8 af[4], bfr[4];
#pragma unroll
            for (int i = 0; i < 4; ++i) {
                const int r = wm + i * 16 + l16;
                const int slot = r * 8 + ((kk * 4 + quad) ^ (r & 7));
                af[i] = *(const bf16x8*)&As[slot * 8];
            }
#pragma unroll
            for (int j = 0; j < 4; ++j) {
                const int r = wn + j * 16 + l16;
                const int slot = r * 8 + ((kk * 4 + quad) ^ (r & 7));
                bfr[j] = *(const bf16x8*)&Bs[slot * 8];
            }
#pragma unroll
            for (int i = 0; i < 4; ++i)
#pragma unroll
                for (int j = 0; j < 4; ++j)
                    acc[i][j] = __builtin_amdgcn_mfma_f32_16x16x32_bf16(
                        af[i], bfr[j], acc[i][j], 0, 0, 0);
        }
    }

#pragma unroll
    for (int i = 0; i < 4; ++i) {
        const int gm = m0 + wm + i * 16 + quad * 4;
#pragma unroll
        for (int j = 0; j < 4; ++j) {
            const int gn = n0 + wn + j * 16 + l16;
            const float bv = bias[gn];
            if (OUT_MODE == 1) {
#pragma unroll
                for (int rr = 0; rr < 4; ++rr)
                    Cf[(size_t)(gm + rr) * 1024 + gn] = acc[i][j][rr] + bv;
            } else {
                const int sel = gn >> 10;
                if (sel == 0) {
#pragma unroll
                    for (int rr = 0; rr < 4; ++rr)
                        Qb[(size_t)(gm + rr) * 1024 + gn] = f2bf(acc[i][j][rr] + bv);
                } else if (sel == 1) {
                    const int col = gn & 1023;
#pragma unroll
                    for (int rr = 0; rr < 4; ++rr)
                        Kb[(size_t)(gm + rr) * 1024 + col] = f2bf(acc[i][j][rr] + bv);
                } else {
                    const int d = gn & 1023;
                    const int head = d >> 6, dl = d & 63;
                    const int b = gm >> 11, key = gm & 2047;
                    ushort4 vv;
                    vv.x = f2bf(acc[i][j][0] + bv);
                    vv.y = f2bf(acc[i][j][1] + bv);
                    vv.z = f2bf(acc[i][j][2] + bv);
                    vv.w = f2bf(acc[i][j][3] + bv);
                    *(ushort4*)&Vt[((size_t)((b * 16 + head) * 64 + dl)) * 2048 + key] = vv;
                }
            }
        }
    }
}

// ---------------------------------------------------------------------------
// MFMA attention v13 (kept from R8 — attn dropped out of the top-5 there):
// v11 structure (in-register P via key-interleave, MFMA row-sum denominator,
// NO setprio) at 512 threads / 8 waves / 256 q per block. Per-block staging
// at 256 q halves total K/V staging traffic (16 -> 8 sweeps per (b,head))
// and halves per-wave gld_lds issue + address VALU. 2 blocks/CU x 8 waves =
// 16 waves/CU, LDS 32KB/block. Per-wave math identical to v11.
// ---------------------------------------------------------------------------
__global__ __launch_bounds__(512, 4) void attn_mfma(
    const unsigned short* __restrict__ Qb, const unsigned short* __restrict__ Kb,
    const unsigned short* __restrict__ Vt, unsigned short* __restrict__ O)
{
    __shared__ unsigned short Ks[2][64 * 64];   // [buf][key][d] swizzled (sg)
    __shared__ unsigned short Vs[2][64 * 64];   // [buf][d][key] swizzled (r&7)

    const int t = threadIdx.x;
    const int w = t >> 6, lane = t & 63;        // w in 0..7
    const int quad = lane >> 4, l16 = lane & 15;
    const int bh = blockIdx.x;                  // fast axis: (b,head)
    const int b = bh >> 4, head = bh & 15;
    const int qbase = blockIdx.y * 256 + w * 32;

    // Q fragments (B-operand of S^T = K Q^T): lane l16 = q-col, regs = d.
    bf16x8 qa[2][2];
#pragma unroll
    for (int s = 0; s < 2; ++s)
#pragma unroll
        for (int h = 0; h < 2; ++h) {
            size_t off = (size_t)(b * SEQ + qbase + s*16 + l16) * D_MODEL
                       + head * HEAD_DIM + h*32 + quad*8;
            qa[s][h] = *(const bf16x8*)(Qb + off);
        }

    f32x4 acc[2][4];     // [strip][d-tile], C-layout row=q, col=d
    f32x4 acc_sum[2];    // row sums via MFMA(P, ones): denom(q) broadcast to all cols
#pragma unroll
    for (int s = 0; s < 2; ++s) {
#pragma unroll
        for (int dt = 0; dt < 4; ++dt) acc[s][dt] = (f32x4){0.f,0.f,0.f,0.f};
        acc_sum[s] = (f32x4){0.f,0.f,0.f,0.f};
    }

    // all-ones bf16 B-operand (1.0bf16 = 0x3F80)
    bf16x8 vones;
#pragma unroll
    for (int i = 0; i < 8; ++i) vones[i] = (short)0x3F80;

    const size_t kbase  = (size_t)(b * SEQ) * D_MODEL + head * HEAD_DIM;
    const size_t vtbase = (size_t)((b * NUM_HEADS + head) * HEAD_DIM) * SEQ;

    // staging: 8 waves cover the 8 segs of each tile (1 K + 1 V per wave)
    const int r  = t >> 3;                      // 0..63 (row of 64-row tile)
    const int ck = (t & 7) ^ ((r & 3) | ((r >> 1) & 4));
    const int cv = (t & 7) ^ (r & 7);

    // prologue: stage k-block 0 into buffer 0
    gld_lds16(Kb + kbase + (size_t)r * D_MODEL + ck * 8, &Ks[0][w * 512]);
    gld_lds16(Vt + vtbase + (size_t)r * SEQ + cv * 8, &Vs[0][w * 512]);

    int ib = 0;
    for (int kb = 0; kb < SEQ; kb += 64, ib ^= 1) {
        __syncthreads();   // buf ib staged

        if (kb + 64 < SEQ) {
            gld_lds16(Kb + kbase + (size_t)(kb + 64 + r) * D_MODEL + ck * 8,
                      &Ks[ib ^ 1][w * 512]);
            gld_lds16(Vt + vtbase + (size_t)r * SEQ + kb + 64 + cv * 8,
                      &Vs[ib ^ 1][w * 512]);
        }

        // K fragments, permuted rows (A-row a holds key kh*32+(a>>2)*8+m*4+(a&3))
        bf16x8 kf[2][2][2];   // [kh][m][h]
#pragma unroll
        for (int kh = 0; kh < 2; ++kh)
#pragma unroll
            for (int m = 0; m < 2; ++m) {
                const int rk = kh * 32 + ((l16 >> 2) << 3) + m * 4 + (l16 & 3);
                const int sg = (rk & 3) | ((rk >> 1) & 4);
#pragma unroll
                for (int h = 0; h < 2; ++h) {
                    const int cc = (h * 4 + quad) ^ sg;
                    kf[kh][m][h] = *(const bf16x8*)&Ks[ib][(rk * 8 + cc) * 8];
                }
            }

#pragma unroll
        for (int kh = 0; kh < 2; ++kh) {
            // S^T = K Q^T with interleaved key rows; exp2; pack -> in-reg pf
            bf16x8 pf[2];
#pragma unroll
            for (int s = 0; s < 2; ++s) {
                f32x4 st0 = (f32x4){0.f,0.f,0.f,0.f};
                f32x4 st1 = (f32x4){0.f,0.f,0.f,0.f};
#pragma unroll
                for (int h = 0; h < 2; ++h) {
                    st0 = __builtin_amdgcn_mfma_f32_16x16x32_bf16(
                        kf[kh][0][h], qa[s][h], st0, 0, 0, 0);
                    st1 = __builtin_amdgcn_mfma_f32_16x16x32_bf16(
                        kf[kh][1][h], qa[s][h], st1, 0, 0, 0);
                }
                // lane holds keys kh*32 + quad*8 + {0..7} for q = s*16+l16
                float p0 = __builtin_amdgcn_exp2f(st0[0]);
                float p1 = __builtin_amdgcn_exp2f(st0[1]);
                float p2 = __builtin_amdgcn_exp2f(st0[2]);
                float p3 = __builtin_amdgcn_exp2f(st0[3]);
                float p4 = __builtin_amdgcn_exp2f(st1[0]);
                float p5 = __builtin_amdgcn_exp2f(st1[1]);
                float p6 = __builtin_amdgcn_exp2f(st1[2]);
                float p7 = __builtin_amdgcn_exp2f(st1[3]);
                __hip_bfloat162 w0 = __float22bfloat162_rn(make_float2(p0, p1));
                __hip_bfloat162 w1 = __float22bfloat162_rn(make_float2(p2, p3));
                __hip_bfloat162 w2 = __float22bfloat162_rn(make_float2(p4, p5));
                __hip_bfloat162 w3 = __float22bfloat162_rn(make_float2(p6, p7));
                union { bf16x8 v; unsigned int u[4]; } pu;
                pu.u[0] = *reinterpret_cast<unsigned int*>(&w0);
                pu.u[1] = *reinterpret_cast<unsigned int*>(&w1);
                pu.u[2] = *reinterpret_cast<unsigned int*>(&w2);
                pu.u[3] = *reinterpret_cast<unsigned int*>(&w3);
                pf[s] = pu.v;
            }

            // O += P V (pf in-register, vf from LDS); row-sum via MFMA(P, 1)
#pragma unroll
            for (int dt = 0; dt < 4; ++dt) {
                const int rv = dt * 16 + l16;
                const int cvv = (kh * 4 + quad) ^ (rv & 7);
                bf16x8 vf = *(const bf16x8*)&Vs[ib][(rv * 8 + cvv) * 8];
#pragma unroll
                for (int s = 0; s < 2; ++s)
                    acc[s][dt] = __builtin_amdgcn_mfma_f32_16x16x32_bf16(
                        pf[s], vf, acc[s][dt], 0, 0, 0);
            }
#pragma unroll
            for (int s = 0; s < 2; ++s)
                acc_sum[s] = __builtin_amdgcn_mfma_f32_16x16x32_bf16(
                    pf[s], vones, acc_sum[s], 0, 0, 0);
        }
    }

    // epilogue: denom(q = s*16+quad*4+rr) is in acc_sum[s][rr] of every lane
#pragma unroll
    for (int s = 0; s < 2; ++s)
#pragma unroll
        for (int rr = 0; rr < 4; ++rr) {
            float inv = 1.0f / acc_sum[s][rr];
            int q = qbase + s*16 + quad*4 + rr;
            unsigned short* orow = O + (size_t)(b * SEQ + q) * D_MODEL + head * HEAD_DIM + l16;
#pragma unroll
            for (int dt = 0; dt < 4; ++dt) orow[dt*16] = f2bf(acc[s][dt][rr] * inv);
        }
}

extern "C" void kernel_launch(void* const* d_in, const int* in_sizes, int n_in,
                              void* d_out, int out_size, void* d_ws, size_t ws_size,
                              hipStream_t stream) {
    const float* x    = (const float*)d_in[0];
    const float* wq_c = (const float*)d_in[1];
    const float* wq_b = (const float*)d_in[2];
    const float* wk_c = (const float*)d_in[3];
    const float* wk_b = (const float*)d_in[4];
    const float* wv_c = (const float*)d_in[5];
    const float* wv_b = (const float*)d_in[6];
    const float* wo_c = (const float*)d_in[7];
    const float* wo_b = (const float*)d_in[8];
    float* out = (float*)d_out;

    char* ws = (char*)d_ws;
    unsigned short* Wt   = (unsigned short*)(ws);                        // 8 MB
    float*          bias = (float*)(ws + ((size_t)8  << 20));            // 16 KB
    unsigned short* xb   = (unsigned short*)(ws + ((size_t)10 << 20));   // 16 MB
    unsigned short* Qb   = (unsigned short*)(ws + ((size_t)26 << 20));   // 16 MB
    unsigned short* Kb   = (unsigned short*)(ws + ((size_t)42 << 20));   // 16 MB
    unsigned short* Vt   = (unsigned short*)(ws + ((size_t)58 << 20));   // 16 MB
    unsigned short* Ob   = (unsigned short*)(ws + ((size_t)74 << 20));   // 16 MB

    prep<<<4096 + MROWS, 256, 0, stream>>>(wq_c, wk_c, wv_c, wo_c,
                                           wq_b, wk_b, wv_b, wo_b,
                                           Wt, bias, x, xb);
    gemm_circ<0><<<dim3(64, 24), 256, 0, stream>>>(xb, Wt, bias, Qb, Kb, Vt, nullptr);
    // fast axis = (b,head): round-robin over XCDs; q-tiles (slow) revisit warm L2
    attn_mfma<<<dim3(BATCH * NUM_HEADS, SEQ / 256), 512, 0, stream>>>(Qb, Kb, Vt, Ob);
    gemm_circ<1><<<dim3(64, 8), 256, 0, stream>>>(Ob, Wt + (size_t)3072 * 1024,
                                                  bias + 3072, nullptr, nullptr, nullptr, out);
}

// Round 11
// 240.210 us; speedup vs baseline: 1.1603x; 1.0201x over previous
//
#include <hip/hip_runtime.h>
#include <hip/hip_bf16.h>

#define D_MODEL 1024
#define NUM_HEADS 16
#define HEAD_DIM 64
#define BATCH 4
#define SEQ 2048
#define MROWS (BATCH * SEQ)

using f32x4  = __attribute__((ext_vector_type(4))) float;
using bf16x8 = __attribute__((ext_vector_type(8))) short;

__device__ inline unsigned short f2bf(float f) {
    __hip_bfloat16 h = __float2bfloat16(f);
    return *reinterpret_cast<unsigned short*>(&h);
}

// async global->LDS, 16B per lane; lds base must be wave-uniform
__device__ inline void gld_lds16(const unsigned short* g, unsigned short* l) {
    __builtin_amdgcn_global_load_lds(
        (const __attribute__((address_space(1))) unsigned int*)g,
        (__attribute__((address_space(3))) unsigned int*)l, 16, 0, 0);
}

#define QSCALE 0.18033688011112042f   // 0.125 / ln(2)

// ---------------------------------------------------------------------------
// prep = build_w + xcast fused into ONE launch (disjoint work, blockIdx
// partition).
//   bid <  4096 : build circulant weights, B^T layout Wt[n][k]=c[(n-k)&1023],
//                 Wq/bq pre-scaled by QSCALE (attn uses exp2 directly).
//   bid >= 4096 : cast x (f32) -> xb (bf16), 1024 elems per block.
// ---------------------------------------------------------------------------
__global__ __launch_bounds__(256) void prep(
    const float* __restrict__ cq, const float* __restrict__ ck,
    const float* __restrict__ cv, const float* __restrict__ co,
    const float* __restrict__ bq, const float* __restrict__ bk,
    const float* __restrict__ bv, const float* __restrict__ bo,
    unsigned short* __restrict__ Wt, float* __restrict__ bias,
    const float* __restrict__ x, unsigned short* __restrict__ xb)
{
    const int bid = blockIdx.x;
    const int t = threadIdx.x;
    if (bid < 4096) {
        const int n = bid;
        const int sel = n >> 10, nl = n & 1023;
        const float* c  = sel == 0 ? cq : sel == 1 ? ck : sel == 2 ? cv : co;
        const float* bb = sel == 0 ? bq : sel == 1 ? bk : sel == 2 ? bv : bo;
        const float sc = (sel == 0) ? QSCALE : 1.0f;
        ushort4 o;
        o.x = f2bf(sc * c[(nl - (4*t + 0)) & 1023]);
        o.y = f2bf(sc * c[(nl - (4*t + 1)) & 1023]);
        o.z = f2bf(sc * c[(nl - (4*t + 2)) & 1023]);
        o.w = f2bf(sc * c[(nl - (4*t + 3)) & 1023]);
        ((ushort4*)(Wt + (size_t)n * 1024))[t] = o;
        if (t == 0) bias[n] = sc * bb[nl];
    } else {
        const size_t i = (size_t)(bid - 4096) * 1024 + t * 4;
        float4 v = *(const float4*)(x + i);
        ushort4 o;
        o.x = f2bf(v.x); o.y = f2bf(v.y); o.z = f2bf(v.z); o.w = f2bf(v.w);
        *(ushort4*)(xb + i) = o;
    }
}

// ---------------------------------------------------------------------------
// bf16 GEMM: C = A * W + bias. 128x128 tile, BK=64, XOR swizzle, gld_lds16.
// Proven m97 structure, natural dispatch order (R8 swizzle reverted).
// OUT_MODE 0: Q row-major; K row-major; V transposed per (b,head).
// OUT_MODE 1: fp32 out.
// ---------------------------------------------------------------------------
template <int OUT_MODE>
__global__ __launch_bounds__(256, 3) void gemm_circ(
    const unsigned short* __restrict__ A,
    const unsigned short* __restrict__ Bt,
    const float* __restrict__ bias,
    unsigned short* __restrict__ Qb, unsigned short* __restrict__ Kb,
    unsigned short* __restrict__ Vt, float* __restrict__ Cf)
{
    __shared__ unsigned short As[128 * 64];
    __shared__ unsigned short Bs[128 * 64];
    const int t = threadIdx.x;
    const int w = t >> 6, lane = t & 63;
    const int quad = lane >> 4, l16 = lane & 15;
    const int m0 = blockIdx.x * 128;
    const int n0 = blockIdx.y * 128;
    const int wm = (w & 1) * 64, wn = (w >> 1) * 64;

    f32x4 acc[4][4];
#pragma unroll
    for (int i = 0; i < 4; ++i)
#pragma unroll
        for (int j = 0; j < 4; ++j) acc[i][j] = (f32x4){0.f, 0.f, 0.f, 0.f};

    for (int k0 = 0; k0 < 1024; k0 += 64) {
        __syncthreads();
#pragma unroll
        for (int j = 0; j < 4; ++j) {
            const int s = j * 4 + w;
            const int i = s * 64 + lane;
            const int r = i >> 3;
            const int c = (i & 7) ^ (r & 7);
            gld_lds16(A  + (size_t)(m0 + r) * 1024 + k0 + c * 8, &As[s * 512]);
            gld_lds16(Bt + (size_t)(n0 + r) * 1024 + k0 + c * 8, &Bs[s * 512]);
        }
        __syncthreads();

#pragma unroll
        for (int kk = 0; kk < 2; ++kk) {
            bf16x8 af[4], bfr[4];
#pragma unroll
            for (int i = 0; i < 4; ++i) {
                const int r = wm + i * 16 + l16;
                const int slot = r * 8 + ((kk * 4 + quad) ^ (r & 7));
                af[i] = *(const bf16x8*)&As[slot * 8];
            }
#pragma unroll
            for (int j = 0; j < 4; ++j) {
                const int r = wn + j * 16 + l16;
                const int slot = r * 8 + ((kk * 4 + quad) ^ (r & 7));
                bfr[j] = *(const bf16x8*)&Bs[slot * 8];
            }
#pragma unroll
            for (int i = 0; i < 4; ++i)
#pragma unroll
                for (int j = 0; j < 4; ++j)
                    acc[i][j] = __builtin_amdgcn_mfma_f32_16x16x32_bf16(
                        af[i], bfr[j], acc[i][j], 0, 0, 0);
        }
    }

#pragma unroll
    for (int i = 0; i < 4; ++i) {
        const int gm = m0 + wm + i * 16 + quad * 4;
#pragma unroll
        for (int j = 0; j < 4; ++j) {
            const int gn = n0 + wn + j * 16 + l16;
            const float bv = bias[gn];
            if (OUT_MODE == 1) {
#pragma unroll
                for (int rr = 0; rr < 4; ++rr)
                    Cf[(size_t)(gm + rr) * 1024 + gn] = acc[i][j][rr] + bv;
            } else {
                const int sel = gn >> 10;
                if (sel == 0) {
#pragma unroll
                    for (int rr = 0; rr < 4; ++rr)
                        Qb[(size_t)(gm + rr) * 1024 + gn] = f2bf(acc[i][j][rr] + bv);
                } else if (sel == 1) {
                    const int col = gn & 1023;
#pragma unroll
                    for (int rr = 0; rr < 4; ++rr)
                        Kb[(size_t)(gm + rr) * 1024 + col] = f2bf(acc[i][j][rr] + bv);
                } else {
                    const int d = gn & 1023;
                    const int head = d >> 6, dl = d & 63;
                    const int b = gm >> 11, key = gm & 2047;
                    ushort4 vv;
                    vv.x = f2bf(acc[i][j][0] + bv);
                    vv.y = f2bf(acc[i][j][1] + bv);
                    vv.z = f2bf(acc[i][j][2] + bv);
                    vv.w = f2bf(acc[i][j][3] + bv);
                    *(ushort4*)&Vt[((size_t)((b * 16 + head) * 64 + dl)) * 2048 + key] = vv;
                }
            }
        }
    }
}

// ---------------------------------------------------------------------------
// MFMA attention v14 = v13 (512 threads, 8 waves, 256 q/block, in-register P
// via key-interleave, MFMA row-sum denominator, NO setprio) + KVBLK=128:
// double the K/V tile per iteration. Barriers halve (32 -> 16), and the
// staging->consumption window doubles (loads issued at iter top consumed a
// full 128-key block later) -> 2x latency tolerance on K/V L2 misses.
// LDS 64KB/block, 2 blocks/CU (grid = 2/CU exactly). Key accumulation order
// unchanged -> bitwise-identical output to v13.
// ---------------------------------------------------------------------------
__global__ __launch_bounds__(512, 4) void attn_mfma(
    const unsigned short* __restrict__ Qb, const unsigned short* __restrict__ Kb,
    const unsigned short* __restrict__ Vt, unsigned short* __restrict__ O)
{
    __shared__ unsigned short Ks[2][128 * 64];  // [buf][key][d] swizzled (sg), 8 chunks/row
    __shared__ unsigned short Vs[2][64 * 128];  // [buf][d][key] swizzled (r&7), 16 chunks/row

    const int t = threadIdx.x;
    const int w = t >> 6, lane = t & 63;        // w in 0..7
    const int quad = lane >> 4, l16 = lane & 15;
    const int bh = blockIdx.x;                  // fast axis: (b,head)
    const int b = bh >> 4, head = bh & 15;
    const int qbase = blockIdx.y * 256 + w * 32;

    // Q fragments (B-operand of S^T = K Q^T): lane l16 = q-col, regs = d.
    bf16x8 qa[2][2];
#pragma unroll
    for (int s = 0; s < 2; ++s)
#pragma unroll
        for (int h = 0; h < 2; ++h) {
            size_t off = (size_t)(b * SEQ + qbase + s*16 + l16) * D_MODEL
                       + head * HEAD_DIM + h*32 + quad*8;
            qa[s][h] = *(const bf16x8*)(Qb + off);
        }

    f32x4 acc[2][4];     // [strip][d-tile], C-layout row=q, col=d
    f32x4 acc_sum[2];    // row sums via MFMA(P, ones): denom(q) broadcast to all cols
#pragma unroll
    for (int s = 0; s < 2; ++s) {
#pragma unroll
        for (int dt = 0; dt < 4; ++dt) acc[s][dt] = (f32x4){0.f,0.f,0.f,0.f};
        acc_sum[s] = (f32x4){0.f,0.f,0.f,0.f};
    }

    // all-ones bf16 B-operand (1.0bf16 = 0x3F80)
    bf16x8 vones;
#pragma unroll
    for (int i = 0; i < 8; ++i) vones[i] = (short)0x3F80;

    const size_t kbase  = (size_t)(b * SEQ) * D_MODEL + head * HEAD_DIM;
    const size_t vtbase = (size_t)((b * NUM_HEADS + head) * HEAD_DIM) * SEQ;

    // staging, per thread 2 K + 2 V loads per 128-key tile.
    // K tile: 128 rows(key) x 8 chunks(d); chunk i: r=i>>3, c=(i&7)^sg(r).
    const int rK0 = t >> 3;                     // rows 0..63   (i = t)
    const int cK0 = (t & 7) ^ ((rK0 & 3) | ((rK0 >> 1) & 4));
    const int rK1 = rK0 + 64;                   // rows 64..127 (i = 512+t)
    const int cK1 = (t & 7) ^ ((rK1 & 3) | ((rK1 >> 1) & 4));
    // V tile: 64 rows(d) x 16 chunks(key); chunk i: r=i>>4, c=(i&15)^(r&7).
    const int rV0 = t >> 4;                     // rows 0..31   (i = t)
    const int cV0 = (t & 15) ^ (rV0 & 7);
    const int rV1 = rV0 + 32;                   // rows 32..63  (i = 512+t)
    const int cV1 = (t & 15) ^ (rV1 & 7);

    // prologue: stage key-block 0 into buffer 0
    gld_lds16(Kb + kbase + (size_t)rK0 * D_MODEL + cK0 * 8, &Ks[0][w * 512]);
    gld_lds16(Kb + kbase + (size_t)rK1 * D_MODEL + cK1 * 8, &Ks[0][4096 + w * 512]);
    gld_lds16(Vt + vtbase + (size_t)rV0 * SEQ + cV0 * 8, &Vs[0][w * 512]);
    gld_lds16(Vt + vtbase + (size_t)rV1 * SEQ + cV1 * 8, &Vs[0][4096 + w * 512]);

    int ib = 0;
    for (int kb = 0; kb < SEQ; kb += 128, ib ^= 1) {
        __syncthreads();   // buf ib staged

        if (kb + 128 < SEQ) {
            gld_lds16(Kb + kbase + (size_t)(kb + 128 + rK0) * D_MODEL + cK0 * 8,
                      &Ks[ib ^ 1][w * 512]);
            gld_lds16(Kb + kbase + (size_t)(kb + 128 + rK1) * D_MODEL + cK1 * 8,
                      &Ks[ib ^ 1][4096 + w * 512]);
            gld_lds16(Vt + vtbase + (size_t)rV0 * SEQ + kb + 128 + cV0 * 8,
                      &Vs[ib ^ 1][w * 512]);
            gld_lds16(Vt + vtbase + (size_t)rV1 * SEQ + kb + 128 + cV1 * 8,
                      &Vs[ib ^ 1][4096 + w * 512]);
        }

#pragma unroll
        for (int kh = 0; kh < 4; ++kh) {
            // K fragments for this 32-key group, permuted rows
            // (A-row a holds key kh*32 + (a>>2)*8 + m*4 + (a&3))
            bf16x8 kf[2][2];   // [m][h]
#pragma unroll
            for (int m = 0; m < 2; ++m) {
                const int rk = kh * 32 + ((l16 >> 2) << 3) + m * 4 + (l16 & 3);
                const int sg = (rk & 3) | ((rk >> 1) & 4);
#pragma unroll
                for (int h = 0; h < 2; ++h) {
                    const int cc = (h * 4 + quad) ^ sg;
                    kf[m][h] = *(const bf16x8*)&Ks[ib][(rk * 8 + cc) * 8];
                }
            }

            // S^T = K Q^T with interleaved key rows; exp2; pack -> in-reg pf
            bf16x8 pf[2];
#pragma unroll
            for (int s = 0; s < 2; ++s) {
                f32x4 st0 = (f32x4){0.f,0.f,0.f,0.f};
                f32x4 st1 = (f32x4){0.f,0.f,0.f,0.f};
#pragma unroll
                for (int h = 0; h < 2; ++h) {
                    st0 = __builtin_amdgcn_mfma_f32_16x16x32_bf16(
                        kf[0][h], qa[s][h], st0, 0, 0, 0);
                    st1 = __builtin_amdgcn_mfma_f32_16x16x32_bf16(
                        kf[1][h], qa[s][h], st1, 0, 0, 0);
                }
                // lane holds keys kh*32 + quad*8 + {0..7} for q = s*16+l16
                float p0 = __builtin_amdgcn_exp2f(st0[0]);
                float p1 = __builtin_amdgcn_exp2f(st0[1]);
                float p2 = __builtin_amdgcn_exp2f(st0[2]);
                float p3 = __builtin_amdgcn_exp2f(st0[3]);
                float p4 = __builtin_amdgcn_exp2f(st1[0]);
                float p5 = __builtin_amdgcn_exp2f(st1[1]);
                float p6 = __builtin_amdgcn_exp2f(st1[2]);
                float p7 = __builtin_amdgcn_exp2f(st1[3]);
                __hip_bfloat162 w0 = __float22bfloat162_rn(make_float2(p0, p1));
                __hip_bfloat162 w1 = __float22bfloat162_rn(make_float2(p2, p3));
                __hip_bfloat162 w2 = __float22bfloat162_rn(make_float2(p4, p5));
                __hip_bfloat162 w3 = __float22bfloat162_rn(make_float2(p6, p7));
                union { bf16x8 v; unsigned int u[4]; } pu;
                pu.u[0] = *reinterpret_cast<unsigned int*>(&w0);
                pu.u[1] = *reinterpret_cast<unsigned int*>(&w1);
                pu.u[2] = *reinterpret_cast<unsigned int*>(&w2);
                pu.u[3] = *reinterpret_cast<unsigned int*>(&w3);
                pf[s] = pu.v;
            }

            // O += P V (pf in-register, vf from LDS); row-sum via MFMA(P, 1)
#pragma unroll
            for (int dt = 0; dt < 4; ++dt) {
                const int rv = dt * 16 + l16;
                const int cvv = (kh * 4 + quad) ^ (rv & 7);
                bf16x8 vf = *(const bf16x8*)&Vs[ib][(rv * 16 + cvv) * 8];
#pragma unroll
                for (int s = 0; s < 2; ++s)
                    acc[s][dt] = __builtin_amdgcn_mfma_f32_16x16x32_bf16(
                        pf[s], vf, acc[s][dt], 0, 0, 0);
            }
#pragma unroll
            for (int s = 0; s < 2; ++s)
                acc_sum[s] = __builtin_amdgcn_mfma_f32_16x16x32_bf16(
                    pf[s], vones, acc_sum[s], 0, 0, 0);
        }
    }

    // epilogue: denom(q = s*16+quad*4+rr) is in acc_sum[s][rr] of every lane
#pragma unroll
    for (int s = 0; s < 2; ++s)
#pragma unroll
        for (int rr = 0; rr < 4; ++rr) {
            float inv = 1.0f / acc_sum[s][rr];
            int q = qbase + s*16 + quad*4 + rr;
            unsigned short* orow = O + (size_t)(b * SEQ + q) * D_MODEL + head * HEAD_DIM + l16;
#pragma unroll
            for (int dt = 0; dt < 4; ++dt) orow[dt*16] = f2bf(acc[s][dt][rr] * inv);
        }
}

extern "C" void kernel_launch(void* const* d_in, const int* in_sizes, int n_in,
                              void* d_out, int out_size, void* d_ws, size_t ws_size,
                              hipStream_t stream) {
    const float* x    = (const float*)d_in[0];
    const float* wq_c = (const float*)d_in[1];
    const float* wq_b = (const float*)d_in[2];
    const float* wk_c = (const float*)d_in[3];
    const float* wk_b = (const float*)d_in[4];
    const float* wv_c = (const float*)d_in[5];
    const float* wv_b = (const float*)d_in[6];
    const float* wo_c = (const float*)d_in[7];
    const float* wo_b = (const float*)d_in[8];
    float* out = (float*)d_out;

    char* ws = (char*)d_ws;
    unsigned short* Wt   = (unsigned short*)(ws);                        // 8 MB
    float*          bias = (float*)(ws + ((size_t)8  << 20));            // 16 KB
    unsigned short* xb   = (unsigned short*)(ws + ((size_t)10 << 20));   // 16 MB
    unsigned short* Qb   = (unsigned short*)(ws + ((size_t)26 << 20));   // 16 MB
    unsigned short* Kb   = (unsigned short*)(ws + ((size_t)42 << 20));   // 16 MB
    unsigned short* Vt   = (unsigned short*)(ws + ((size_t)58 << 20));   // 16 MB
    unsigned short* Ob   = (unsigned short*)(ws + ((size_t)74 << 20));   // 16 MB

    prep<<<4096 + MROWS, 256, 0, stream>>>(wq_c, wk_c, wv_c, wo_c,
                                           wq_b, wk_b, wv_b, wo_b,
                                           Wt, bias, x, xb);
    gemm_circ<0><<<dim3(64, 24), 256, 0, stream>>>(xb, Wt, bias, Qb, Kb, Vt, nullptr);
    // fast axis = (b,head): round-robin over XCDs; q-tiles (slow) revisit warm L2
    attn_mfma<<<dim3(BATCH * NUM_HEADS, SEQ / 256), 512, 0, stream>>>(Qb, Kb, Vt, Ob);
    gemm_circ<1><<<dim3(64, 8), 256, 0, stream>>>(Ob, Wt + (size_t)3072 * 1024,
                                                  bias + 3072, nullptr, nullptr, nullptr, out);
}

// Round 12
// 239.318 us; speedup vs baseline: 1.1647x; 1.0037x over previous
//
#include <hip/hip_runtime.h>
#include <hip/hip_bf16.h>

#define D_MODEL 1024
#define NUM_HEADS 16
#define HEAD_DIM 64
#define BATCH 4
#define SEQ 2048
#define MROWS (BATCH * SEQ)

using f32x4  = __attribute__((ext_vector_type(4))) float;
using bf16x8 = __attribute__((ext_vector_type(8))) short;

__device__ inline unsigned short f2bf(float f) {
    __hip_bfloat16 h = __float2bfloat16(f);
    return *reinterpret_cast<unsigned short*>(&h);
}

// async global->LDS, 16B per lane; lds base must be wave-uniform
__device__ inline void gld_lds16(const unsigned short* g, unsigned short* l) {
    __builtin_amdgcn_global_load_lds(
        (const __attribute__((address_space(1))) unsigned int*)g,
        (__attribute__((address_space(3))) unsigned int*)l, 16, 0, 0);
}

#define QSCALE 0.18033688011112042f   // 0.125 / ln(2)

// ---------------------------------------------------------------------------
// prep = build_w + xcast fused into ONE launch (disjoint work, blockIdx
// partition).
//   bid <  4096 : build circulant weights, B^T layout Wt[n][k]=c[(n-k)&1023],
//                 Wq/bq pre-scaled by QSCALE (attn uses exp2 directly).
//   bid >= 4096 : cast x (f32) -> xb (bf16), 1024 elems per block.
// ---------------------------------------------------------------------------
__global__ __launch_bounds__(256) void prep(
    const float* __restrict__ cq, const float* __restrict__ ck,
    const float* __restrict__ cv, const float* __restrict__ co,
    const float* __restrict__ bq, const float* __restrict__ bk,
    const float* __restrict__ bv, const float* __restrict__ bo,
    unsigned short* __restrict__ Wt, float* __restrict__ bias,
    const float* __restrict__ x, unsigned short* __restrict__ xb)
{
    const int bid = blockIdx.x;
    const int t = threadIdx.x;
    if (bid < 4096) {
        const int n = bid;
        const int sel = n >> 10, nl = n & 1023;
        const float* c  = sel == 0 ? cq : sel == 1 ? ck : sel == 2 ? cv : co;
        const float* bb = sel == 0 ? bq : sel == 1 ? bk : sel == 2 ? bv : bo;
        const float sc = (sel == 0) ? QSCALE : 1.0f;
        ushort4 o;
        o.x = f2bf(sc * c[(nl - (4*t + 0)) & 1023]);
        o.y = f2bf(sc * c[(nl - (4*t + 1)) & 1023]);
        o.z = f2bf(sc * c[(nl - (4*t + 2)) & 1023]);
        o.w = f2bf(sc * c[(nl - (4*t + 3)) & 1023]);
        ((ushort4*)(Wt + (size_t)n * 1024))[t] = o;
        if (t == 0) bias[n] = sc * bb[nl];
    } else {
        const size_t i = (size_t)(bid - 4096) * 1024 + t * 4;
        float4 v = *(const float4*)(x + i);
        ushort4 o;
        o.x = f2bf(v.x); o.y = f2bf(v.y); o.z = f2bf(v.z); o.w = f2bf(v.w);
        *(ushort4*)(xb + i) = o;
    }
}

// ---------------------------------------------------------------------------
// bf16 GEMM: C = A * W + bias. 128x128 tile, BK=64, XOR swizzle, gld_lds16.
// Proven m97 structure, natural dispatch order (R8 swizzle reverted).
// OUT_MODE 0: Q row-major; K row-major; V transposed per (b,head).
// OUT_MODE 1: fp32 out.
// ---------------------------------------------------------------------------
template <int OUT_MODE>
__global__ __launch_bounds__(256, 3) void gemm_circ(
    const unsigned short* __restrict__ A,
    const unsigned short* __restrict__ Bt,
    const float* __restrict__ bias,
    unsigned short* __restrict__ Qb, unsigned short* __restrict__ Kb,
    unsigned short* __restrict__ Vt, float* __restrict__ Cf)
{
    __shared__ unsigned short As[128 * 64];
    __shared__ unsigned short Bs[128 * 64];
    const int t = threadIdx.x;
    const int w = t >> 6, lane = t & 63;
    const int quad = lane >> 4, l16 = lane & 15;
    const int m0 = blockIdx.x * 128;
    const int n0 = blockIdx.y * 128;
    const int wm = (w & 1) * 64, wn = (w >> 1) * 64;

    f32x4 acc[4][4];
#pragma unroll
    for (int i = 0; i < 4; ++i)
#pragma unroll
        for (int j = 0; j < 4; ++j) acc[i][j] = (f32x4){0.f, 0.f, 0.f, 0.f};

    for (int k0 = 0; k0 < 1024; k0 += 64) {
        __syncthreads();
#pragma unroll
        for (int j = 0; j < 4; ++j) {
            const int s = j * 4 + w;
            const int i = s * 64 + lane;
            const int r = i >> 3;
            const int c = (i & 7) ^ (r & 7);
            gld_lds16(A  + (size_t)(m0 + r) * 1024 + k0 + c * 8, &As[s * 512]);
            gld_lds16(Bt + (size_t)(n0 + r) * 1024 + k0 + c * 8, &Bs[s * 512]);
        }
        __syncthreads();

#pragma unroll
        for (int kk = 0; kk < 2; ++kk) {
            bf16x8 af[4], bfr[4];
#pragma unroll
            for (int i = 0; i < 4; ++i) {
                const int r = wm + i * 16 + l16;
                const int slot = r * 8 + ((kk * 4 + quad) ^ (r & 7));
                af[i] = *(const bf16x8*)&As[slot * 8];
            }
#pragma unroll
            for (int j = 0; j < 4; ++j) {
                const int r = wn + j * 16 + l16;
                const int slot = r * 8 + ((kk * 4 + quad) ^ (r & 7));
                bfr[j] = *(const bf16x8*)&Bs[slot * 8];
            }
#pragma unroll
            for (int i = 0; i < 4; ++i)
#pragma unroll
                for (int j = 0; j < 4; ++j)
                    acc[i][j] = __builtin_amdgcn_mfma_f32_16x16x32_bf16(
                        af[i], bfr[j], acc[i][j], 0, 0, 0);
        }
    }

#pragma unroll
    for (int i = 0; i < 4; ++i) {
        const int gm = m0 + wm + i * 16 + quad * 4;
#pragma unroll
        for (int j = 0; j < 4; ++j) {
            const int gn = n0 + wn + j * 16 + l16;
            const float bv = bias[gn];
            if (OUT_MODE == 1) {
#pragma unroll
                for (int rr = 0; rr < 4; ++rr)
                    Cf[(size_t)(gm + rr) * 1024 + gn] = acc[i][j][rr] + bv;
            } else {
                const int sel = gn >> 10;
                if (sel == 0) {
#pragma unroll
                    for (int rr = 0; rr < 4; ++rr)
                        Qb[(size_t)(gm + rr) * 1024 + gn] = f2bf(acc[i][j][rr] + bv);
                } else if (sel == 1) {
                    const int col = gn & 1023;
#pragma unroll
                    for (int rr = 0; rr < 4; ++rr)
                        Kb[(size_t)(gm + rr) * 1024 + col] = f2bf(acc[i][j][rr] + bv);
                } else {
                    const int d = gn & 1023;
                    const int head = d >> 6, dl = d & 63;
                    const int b = gm >> 11, key = gm & 2047;
                    ushort4 vv;
                    vv.x = f2bf(acc[i][j][0] + bv);
                    vv.y = f2bf(acc[i][j][1] + bv);
                    vv.z = f2bf(acc[i][j][2] + bv);
                    vv.w = f2bf(acc[i][j][3] + bv);
                    *(ushort4*)&Vt[((size_t)((b * 16 + head) * 64 + dl)) * 2048 + key] = vv;
                }
            }
        }
    }
}

// ---------------------------------------------------------------------------
// MFMA attention v15 = v14 (512 threads, 8 waves, 256 q/block, KVBLK=128,
// in-register P, MFMA row-sum, NO setprio) with the V tile split into TWO
// independent 64-key subtiles, each using v13's measured-zero-conflict
// [d:64][chunk:8] layout (128B rows). v14's single 256B-row V tile measured
// 4.19M bank-conflict cycles (exactly 4x the vf read count); the 128B-row
// pattern measured 0 in v13. Same key order, same values -> bitwise-identical
// output to v13/v14.
// ---------------------------------------------------------------------------
__global__ __launch_bounds__(512, 4) void attn_mfma(
    const unsigned short* __restrict__ Qb, const unsigned short* __restrict__ Kb,
    const unsigned short* __restrict__ Vt, unsigned short* __restrict__ O)
{
    __shared__ unsigned short Ks[2][128 * 64];    // [buf][key][d] swizzled (sg)
    __shared__ unsigned short Vs[2][2][64 * 64];  // [buf][keyhalf][d][key] swz (r&7)

    const int t = threadIdx.x;
    const int w = t >> 6, lane = t & 63;        // w in 0..7
    const int quad = lane >> 4, l16 = lane & 15;
    const int bh = blockIdx.x;                  // fast axis: (b,head)
    const int b = bh >> 4, head = bh & 15;
    const int qbase = blockIdx.y * 256 + w * 32;

    // Q fragments (B-operand of S^T = K Q^T): lane l16 = q-col, regs = d.
    bf16x8 qa[2][2];
#pragma unroll
    for (int s = 0; s < 2; ++s)
#pragma unroll
        for (int h = 0; h < 2; ++h) {
            size_t off = (size_t)(b * SEQ + qbase + s*16 + l16) * D_MODEL
                       + head * HEAD_DIM + h*32 + quad*8;
            qa[s][h] = *(const bf16x8*)(Qb + off);
        }

    f32x4 acc[2][4];     // [strip][d-tile], C-layout row=q, col=d
    f32x4 acc_sum[2];    // row sums via MFMA(P, ones): denom(q) broadcast to all cols
#pragma unroll
    for (int s = 0; s < 2; ++s) {
#pragma unroll
        for (int dt = 0; dt < 4; ++dt) acc[s][dt] = (f32x4){0.f,0.f,0.f,0.f};
        acc_sum[s] = (f32x4){0.f,0.f,0.f,0.f};
    }

    // all-ones bf16 B-operand (1.0bf16 = 0x3F80)
    bf16x8 vones;
#pragma unroll
    for (int i = 0; i < 8; ++i) vones[i] = (short)0x3F80;

    const size_t kbase  = (size_t)(b * SEQ) * D_MODEL + head * HEAD_DIM;
    const size_t vtbase = (size_t)((b * NUM_HEADS + head) * HEAD_DIM) * SEQ;

    // staging, per thread 2 K + 2 V loads per 128-key tile.
    // K tile: 128 rows(key) x 8 chunks(d); chunk i: r=i>>3, c=(i&7)^sg(r).
    const int rK0 = t >> 3;                     // rows 0..63   (i = t)
    const int cK0 = (t & 7) ^ ((rK0 & 3) | ((rK0 >> 1) & 4));
    const int rK1 = rK0 + 64;                   // rows 64..127 (i = 512+t)
    const int cK1 = (t & 7) ^ ((rK1 & 3) | ((rK1 >> 1) & 4));
    // V subtile (64 keys): 64 rows(d) x 8 chunks(key); chunk t: r=t>>3,
    // c=(t&7)^(r&7). Subtile 0 = keys +0..63, subtile 1 = keys +64..127.
    const int rV = t >> 3;
    const int cV = (t & 7) ^ (rV & 7);

    // prologue: stage key-block 0 into buffer 0
    gld_lds16(Kb + kbase + (size_t)rK0 * D_MODEL + cK0 * 8, &Ks[0][w * 512]);
    gld_lds16(Kb + kbase + (size_t)rK1 * D_MODEL + cK1 * 8, &Ks[0][4096 + w * 512]);
    gld_lds16(Vt + vtbase + (size_t)rV * SEQ + cV * 8, &Vs[0][0][w * 512]);
    gld_lds16(Vt + vtbase + (size_t)rV * SEQ + 64 + cV * 8, &Vs[0][1][w * 512]);

    int ib = 0;
    for (int kb = 0; kb < SEQ; kb += 128, ib ^= 1) {
        __syncthreads();   // buf ib staged

        if (kb + 128 < SEQ) {
            gld_lds16(Kb + kbase + (size_t)(kb + 128 + rK0) * D_MODEL + cK0 * 8,
                      &Ks[ib ^ 1][w * 512]);
            gld_lds16(Kb + kbase + (size_t)(kb + 128 + rK1) * D_MODEL + cK1 * 8,
                      &Ks[ib ^ 1][4096 + w * 512]);
            gld_lds16(Vt + vtbase + (size_t)rV * SEQ + kb + 128 + cV * 8,
                      &Vs[ib ^ 1][0][w * 512]);
            gld_lds16(Vt + vtbase + (size_t)rV * SEQ + kb + 192 + cV * 8,
                      &Vs[ib ^ 1][1][w * 512]);
        }

#pragma unroll
        for (int kh = 0; kh < 4; ++kh) {
            // K fragments for this 32-key group, permuted rows
            // (A-row a holds key kh*32 + (a>>2)*8 + m*4 + (a&3))
            bf16x8 kf[2][2];   // [m][h]
#pragma unroll
            for (int m = 0; m < 2; ++m) {
                const int rk = kh * 32 + ((l16 >> 2) << 3) + m * 4 + (l16 & 3);
                const int sg = (rk & 3) | ((rk >> 1) & 4);
#pragma unroll
                for (int h = 0; h < 2; ++h) {
                    const int cc = (h * 4 + quad) ^ sg;
                    kf[m][h] = *(const bf16x8*)&Ks[ib][(rk * 8 + cc) * 8];
                }
            }

            // S^T = K Q^T with interleaved key rows; exp2; pack -> in-reg pf
            bf16x8 pf[2];
#pragma unroll
            for (int s = 0; s < 2; ++s) {
                f32x4 st0 = (f32x4){0.f,0.f,0.f,0.f};
                f32x4 st1 = (f32x4){0.f,0.f,0.f,0.f};
#pragma unroll
                for (int h = 0; h < 2; ++h) {
                    st0 = __builtin_amdgcn_mfma_f32_16x16x32_bf16(
                        kf[0][h], qa[s][h], st0, 0, 0, 0);
                    st1 = __builtin_amdgcn_mfma_f32_16x16x32_bf16(
                        kf[1][h], qa[s][h], st1, 0, 0, 0);
                }
                // lane holds keys kh*32 + quad*8 + {0..7} for q = s*16+l16
                float p0 = __builtin_amdgcn_exp2f(st0[0]);
                float p1 = __builtin_amdgcn_exp2f(st0[1]);
                float p2 = __builtin_amdgcn_exp2f(st0[2]);
                float p3 = __builtin_amdgcn_exp2f(st0[3]);
                float p4 = __builtin_amdgcn_exp2f(st1[0]);
                float p5 = __builtin_amdgcn_exp2f(st1[1]);
                float p6 = __builtin_amdgcn_exp2f(st1[2]);
                float p7 = __builtin_amdgcn_exp2f(st1[3]);
                __hip_bfloat162 w0 = __float22bfloat162_rn(make_float2(p0, p1));
                __hip_bfloat162 w1 = __float22bfloat162_rn(make_float2(p2, p3));
                __hip_bfloat162 w2 = __float22bfloat162_rn(make_float2(p4, p5));
                __hip_bfloat162 w3 = __float22bfloat162_rn(make_float2(p6, p7));
                union { bf16x8 v; unsigned int u[4]; } pu;
                pu.u[0] = *reinterpret_cast<unsigned int*>(&w0);
                pu.u[1] = *reinterpret_cast<unsigned int*>(&w1);
                pu.u[2] = *reinterpret_cast<unsigned int*>(&w2);
                pu.u[3] = *reinterpret_cast<unsigned int*>(&w3);
                pf[s] = pu.v;
            }

            // O += P V (pf in-register, vf from the kh>>1 subtile, v13 layout)
#pragma unroll
            for (int dt = 0; dt < 4; ++dt) {
                const int rv2 = dt * 16 + l16;
                const int cvv = ((kh & 1) * 4 + quad) ^ (rv2 & 7);
                bf16x8 vf = *(const bf16x8*)&Vs[ib][kh >> 1][(rv2 * 8 + cvv) * 8];
#pragma unroll
                for (int s = 0; s < 2; ++s)
                    acc[s][dt] = __builtin_amdgcn_mfma_f32_16x16x32_bf16(
                        pf[s], vf, acc[s][dt], 0, 0, 0);
            }
#pragma unroll
            for (int s = 0; s < 2; ++s)
                acc_sum[s] = __builtin_amdgcn_mfma_f32_16x16x32_bf16(
                    pf[s], vones, acc_sum[s], 0, 0, 0);
        }
    }

    // epilogue: denom(q = s*16+quad*4+rr) is in acc_sum[s][rr] of every lane
#pragma unroll
    for (int s = 0; s < 2; ++s)
#pragma unroll
        for (int rr = 0; rr < 4; ++rr) {
            float inv = 1.0f / acc_sum[s][rr];
            int q = qbase + s*16 + quad*4 + rr;
            unsigned short* orow = O + (size_t)(b * SEQ + q) * D_MODEL + head * HEAD_DIM + l16;
#pragma unroll
            for (int dt = 0; dt < 4; ++dt) orow[dt*16] = f2bf(acc[s][dt][rr] * inv);
        }
}

extern "C" void kernel_launch(void* const* d_in, const int* in_sizes, int n_in,
                              void* d_out, int out_size, void* d_ws, size_t ws_size,
                              hipStream_t stream) {
    const float* x    = (const float*)d_in[0];
    const float* wq_c = (const float*)d_in[1];
    const float* wq_b = (const float*)d_in[2];
    const float* wk_c = (const float*)d_in[3];
    const float* wk_b = (const float*)d_in[4];
    const float* wv_c = (const float*)d_in[5];
    const float* wv_b = (const float*)d_in[6];
    const float* wo_c = (const float*)d_in[7];
    const float* wo_b = (const float*)d_in[8];
    float* out = (float*)d_out;

    char* ws = (char*)d_ws;
    unsigned short* Wt   = (unsigned short*)(ws);                        // 8 MB
    float*          bias = (float*)(ws + ((size_t)8  << 20));            // 16 KB
    unsigned short* xb   = (unsigned short*)(ws + ((size_t)10 << 20));   // 16 MB
    unsigned short* Qb   = (unsigned short*)(ws + ((size_t)26 << 20));   // 16 MB
    unsigned short* Kb   = (unsigned short*)(ws + ((size_t)42 << 20));   // 16 MB
    unsigned short* Vt   = (unsigned short*)(ws + ((size_t)58 << 20));   // 16 MB
    unsigned short* Ob   = (unsigned short*)(ws + ((size_t)74 << 20));   // 16 MB

    prep<<<4096 + MROWS, 256, 0, stream>>>(wq_c, wk_c, wv_c, wo_c,
                                           wq_b, wk_b, wv_b, wo_b,
                                           Wt, bias, x, xb);
    gemm_circ<0><<<dim3(64, 24), 256, 0, stream>>>(xb, Wt, bias, Qb, Kb, Vt, nullptr);
    // fast axis = (b,head): round-robin over XCDs; q-tiles (slow) revisit warm L2
    attn_mfma<<<dim3(BATCH * NUM_HEADS, SEQ / 256), 512, 0, stream>>>(Qb, Kb, Vt, Ob);
    gemm_circ<1><<<dim3(64, 8), 256, 0, stream>>>(Ob, Wt + (size_t)3072 * 1024,
                                                  bias + 3072, nullptr, nullptr, nullptr, out);
}

// Round 14
// 237.663 us; speedup vs baseline: 1.1728x; 1.0070x over previous
//
#include <hip/hip_runtime.h>
#include <hip/hip_bf16.h>

#define D_MODEL 1024
#define NUM_HEADS 16
#define HEAD_DIM 64
#define BATCH 4
#define SEQ 2048
#define MROWS (BATCH * SEQ)

using f32x4  = __attribute__((ext_vector_type(4))) float;
using bf16x8 = __attribute__((ext_vector_type(8))) short;

__device__ inline unsigned short f2bf(float f) {
    __hip_bfloat16 h = __float2bfloat16(f);
    return *reinterpret_cast<unsigned short*>(&h);
}

// async global->LDS, 16B per lane; lds base must be wave-uniform
__device__ inline void gld_lds16(const unsigned short* g, unsigned short* l) {
    __builtin_amdgcn_global_load_lds(
        (const __attribute__((address_space(1))) unsigned int*)g,
        (__attribute__((address_space(3))) unsigned int*)l, 16, 0, 0);
}

#define QSCALE 0.18033688011112042f   // 0.125 / ln(2)

// ---------------------------------------------------------------------------
// prep = build_w + xcast fused into ONE launch (disjoint work, blockIdx
// partition).
//   bid <  4096 : build circulant weights, B^T layout Wt[n][k]=c[(n-k)&1023],
//                 Wq/bq pre-scaled by QSCALE (attn uses exp2 directly).
//   bid >= 4096 : cast x (f32) -> xb (bf16), 1024 elems per block.
// ---------------------------------------------------------------------------
__global__ __launch_bounds__(256) void prep(
    const float* __restrict__ cq, const float* __restrict__ ck,
    const float* __restrict__ cv, const float* __restrict__ co,
    const float* __restrict__ bq, const float* __restrict__ bk,
    const float* __restrict__ bv, const float* __restrict__ bo,
    unsigned short* __restrict__ Wt, float* __restrict__ bias,
    const float* __restrict__ x, unsigned short* __restrict__ xb)
{
    const int bid = blockIdx.x;
    const int t = threadIdx.x;
    if (bid < 4096) {
        const int n = bid;
        const int sel = n >> 10, nl = n & 1023;
        const float* c  = sel == 0 ? cq : sel == 1 ? ck : sel == 2 ? cv : co;
        const float* bb = sel == 0 ? bq : sel == 1 ? bk : sel == 2 ? bv : bo;
        const float sc = (sel == 0) ? QSCALE : 1.0f;
        ushort4 o;
        o.x = f2bf(sc * c[(nl - (4*t + 0)) & 1023]);
        o.y = f2bf(sc * c[(nl - (4*t + 1)) & 1023]);
        o.z = f2bf(sc * c[(nl - (4*t + 2)) & 1023]);
        o.w = f2bf(sc * c[(nl - (4*t + 3)) & 1023]);
        ((ushort4*)(Wt + (size_t)n * 1024))[t] = o;
        if (t == 0) bias[n] = sc * bb[nl];
    } else {
        const size_t i = (size_t)(bid - 4096) * 1024 + t * 4;
        float4 v = *(const float4*)(x + i);
        ushort4 o;
        o.x = f2bf(v.x); o.y = f2bf(v.y); o.z = f2bf(v.z); o.w = f2bf(v.w);
        *(ushort4*)(xb + i) = o;
    }
}

// ---------------------------------------------------------------------------
// bf16 GEMM: C = A * W + bias. 128x128 tile, BK=64, XOR swizzle, gld_lds16.
// Proven m97 structure, natural dispatch order.
// OUT_MODE 0: Q row-major; K row-major; V transposed per (b,head).
// OUT_MODE 1: fp32 out.
// ---------------------------------------------------------------------------
template <int OUT_MODE>
__global__ __launch_bounds__(256, 3) void gemm_circ(
    const unsigned short* __restrict__ A,
    const unsigned short* __restrict__ Bt,
    const float* __restrict__ bias,
    unsigned short* __restrict__ Qb, unsigned short* __restrict__ Kb,
    unsigned short* __restrict__ Vt, float* __restrict__ Cf)
{
    __shared__ unsigned short As[128 * 64];
    __shared__ unsigned short Bs[128 * 64];
    const int t = threadIdx.x;
    const int w = t >> 6, lane = t & 63;
    const int quad = lane >> 4, l16 = lane & 15;
    const int m0 = blockIdx.x * 128;
    const int n0 = blockIdx.y * 128;
    const int wm = (w & 1) * 64, wn = (w >> 1) * 64;

    f32x4 acc[4][4];
#pragma unroll
    for (int i = 0; i < 4; ++i)
#pragma unroll
        for (int j = 0; j < 4; ++j) acc[i][j] = (f32x4){0.f, 0.f, 0.f, 0.f};

    for (int k0 = 0; k0 < 1024; k0 += 64) {
        __syncthreads();
#pragma unroll
        for (int j = 0; j < 4; ++j) {
            const int s = j * 4 + w;
            const int i = s * 64 + lane;
            const int r = i >> 3;
            const int c = (i & 7) ^ (r & 7);
            gld_lds16(A  + (size_t)(m0 + r) * 1024 + k0 + c * 8, &As[s * 512]);
            gld_lds16(Bt + (size_t)(n0 + r) * 1024 + k0 + c * 8, &Bs[s * 512]);
        }
        __syncthreads();

#pragma unroll
        for (int kk = 0; kk < 2; ++kk) {
            bf16x8 af[4], bfr[4];
#pragma unroll
            for (int i = 0; i < 4; ++i) {
                const int r = wm + i * 16 + l16;
                const int slot = r * 8 + ((kk * 4 + quad) ^ (r & 7));
                af[i] = *(const bf16x8*)&As[slot * 8];
            }
#pragma unroll
            for (int j = 0; j < 4; ++j) {
                const int r = wn + j * 16 + l16;
                const int slot = r * 8 + ((kk * 4 + quad) ^ (r & 7));
                bfr[j] = *(const bf16x8*)&Bs[slot * 8];
            }
#pragma unroll
            for (int i = 0; i < 4; ++i)
#pragma unroll
                for (int j = 0; j < 4; ++j)
                    acc[i][j] = __builtin_amdgcn_mfma_f32_16x16x32_bf16(
                        af[i], bfr[j], acc[i][j], 0, 0, 0);
        }
    }

#pragma unroll
    for (int i = 0; i < 4; ++i) {
        const int gm = m0 + wm + i * 16 + quad * 4;
#pragma unroll
        for (int j = 0; j < 4; ++j) {
            const int gn = n0 + wn + j * 16 + l16;
            const float bv = bias[gn];
            if (OUT_MODE == 1) {
#pragma unroll
                for (int rr = 0; rr < 4; ++rr)
                    Cf[(size_t)(gm + rr) * 1024 + gn] = acc[i][j][rr] + bv;
            } else {
                const int sel = gn >> 10;
                if (sel == 0) {
#pragma unroll
                    for (int rr = 0; rr < 4; ++rr)
                        Qb[(size_t)(gm + rr) * 1024 + gn] = f2bf(acc[i][j][rr] + bv);
                } else if (sel == 1) {
                    const int col = gn & 1023;
#pragma unroll
                    for (int rr = 0; rr < 4; ++rr)
                        Kb[(size_t)(gm + rr) * 1024 + col] = f2bf(acc[i][j][rr] + bv);
                } else {
                    const int d = gn & 1023;
                    const int head = d >> 6, dl = d & 63;
                    const int b = gm >> 11, key = gm & 2047;
                    ushort4 vv;
                    vv.x = f2bf(acc[i][j][0] + bv);
                    vv.y = f2bf(acc[i][j][1] + bv);
                    vv.z = f2bf(acc[i][j][2] + bv);
                    vv.w = f2bf(acc[i][j][3] + bv);
                    *(ushort4*)&Vt[((size_t)((b * 16 + head) * 64 + dl)) * 2048 + key] = vv;
                }
            }
        }
    }
}

// ---------------------------------------------------------------------------
// MFMA attention v15 (session best, 81.5us): 512 threads / 8 waves / 256 q
// per block, KVBLK=128, in-register P via key-interleave, MFMA row-sum
// denominator, NO setprio, V tile split into two 64-key subtiles with the
// measured-zero-conflict [d:64][chunk:8] layout.
// ---------------------------------------------------------------------------
__global__ __launch_bounds__(512, 4) void attn_mfma(
    const unsigned short* __restrict__ Qb, const unsigned short* __restrict__ Kb,
    const unsigned short* __restrict__ Vt, unsigned short* __restrict__ O)
{
    __shared__ unsigned short Ks[2][128 * 64];    // [buf][key][d] swizzled (sg)
    __shared__ unsigned short Vs[2][2][64 * 64];  // [buf][keyhalf][d][key] swz (r&7)

    const int t = threadIdx.x;
    const int w = t >> 6, lane = t & 63;        // w in 0..7
    const int quad = lane >> 4, l16 = lane & 15;
    const int bh = blockIdx.x;                  // fast axis: (b,head)
    const int b = bh >> 4, head = bh & 15;
    const int qbase = blockIdx.y * 256 + w * 32;

    // Q fragments (B-operand of S^T = K Q^T): lane l16 = q-col, regs = d.
    bf16x8 qa[2][2];
#pragma unroll
    for (int s = 0; s < 2; ++s)
#pragma unroll
        for (int h = 0; h < 2; ++h) {
            size_t off = (size_t)(b * SEQ + qbase + s*16 + l16) * D_MODEL
                       + head * HEAD_DIM + h*32 + quad*8;
            qa[s][h] = *(const bf16x8*)(Qb + off);
        }

    f32x4 acc[2][4];     // [strip][d-tile], C-layout row=q, col=d
    f32x4 acc_sum[2];    // row sums via MFMA(P, ones): denom(q) broadcast to all cols
#pragma unroll
    for (int s = 0; s < 2; ++s) {
#pragma unroll
        for (int dt = 0; dt < 4; ++dt) acc[s][dt] = (f32x4){0.f,0.f,0.f,0.f};
        acc_sum[s] = (f32x4){0.f,0.f,0.f,0.f};
    }

    // all-ones bf16 B-operand (1.0bf16 = 0x3F80)
    bf16x8 vones;
#pragma unroll
    for (int i = 0; i < 8; ++i) vones[i] = (short)0x3F80;

    const size_t kbase  = (size_t)(b * SEQ) * D_MODEL + head * HEAD_DIM;
    const size_t vtbase = (size_t)((b * NUM_HEADS + head) * HEAD_DIM) * SEQ;

    // staging, per thread 2 K + 2 V loads per 128-key tile.
    // K tile: 128 rows(key) x 8 chunks(d); chunk i: r=i>>3, c=(i&7)^sg(r).
    const int rK0 = t >> 3;                     // rows 0..63   (i = t)
    const int cK0 = (t & 7) ^ ((rK0 & 3) | ((rK0 >> 1) & 4));
    const int rK1 = rK0 + 64;                   // rows 64..127 (i = 512+t)
    const int cK1 = (t & 7) ^ ((rK1 & 3) | ((rK1 >> 1) & 4));
    // V subtile (64 keys): 64 rows(d) x 8 chunks(key); chunk t: r=t>>3,
    // c=(t&7)^(r&7). Subtile 0 = keys +0..63, subtile 1 = keys +64..127.
    const int rV = t >> 3;
    const int cV = (t & 7) ^ (rV & 7);

    // prologue: stage key-block 0 into buffer 0
    gld_lds16(Kb + kbase + (size_t)rK0 * D_MODEL + cK0 * 8, &Ks[0][w * 512]);
    gld_lds16(Kb + kbase + (size_t)rK1 * D_MODEL + cK1 * 8, &Ks[0][4096 + w * 512]);
    gld_lds16(Vt + vtbase + (size_t)rV * SEQ + cV * 8, &Vs[0][0][w * 512]);
    gld_lds16(Vt + vtbase + (size_t)rV * SEQ + 64 + cV * 8, &Vs[0][1][w * 512]);

    int ib = 0;
    for (int kb = 0; kb < SEQ; kb += 128, ib ^= 1) {
        __syncthreads();   // buf ib staged

        if (kb + 128 < SEQ) {
            gld_lds16(Kb + kbase + (size_t)(kb + 128 + rK0) * D_MODEL + cK0 * 8,
                      &Ks[ib ^ 1][w * 512]);
            gld_lds16(Kb + kbase + (size_t)(kb + 128 + rK1) * D_MODEL + cK1 * 8,
                      &Ks[ib ^ 1][4096 + w * 512]);
            gld_lds16(Vt + vtbase + (size_t)rV * SEQ + kb + 128 + cV * 8,
                      &Vs[ib ^ 1][0][w * 512]);
            gld_lds16(Vt + vtbase + (size_t)rV * SEQ + kb + 192 + cV * 8,
                      &Vs[ib ^ 1][1][w * 512]);
        }

#pragma unroll
        for (int kh = 0; kh < 4; ++kh) {
            // K fragments for this 32-key group, permuted rows
            // (A-row a holds key kh*32 + (a>>2)*8 + m*4 + (a&3))
            bf16x8 kf[2][2];   // [m][h]
#pragma unroll
            for (int m = 0; m < 2; ++m) {
                const int rk = kh * 32 + ((l16 >> 2) << 3) + m * 4 + (l16 & 3);
                const int sg = (rk & 3) | ((rk >> 1) & 4);
#pragma unroll
                for (int h = 0; h < 2; ++h) {
                    const int cc = (h * 4 + quad) ^ sg;
                    kf[m][h] = *(const bf16x8*)&Ks[ib][(rk * 8 + cc) * 8];
                }
            }

            // S^T = K Q^T with interleaved key rows; exp2; pack -> in-reg pf
            bf16x8 pf[2];
#pragma unroll
            for (int s = 0; s < 2; ++s) {
                f32x4 st0 = (f32x4){0.f,0.f,0.f,0.f};
                f32x4 st1 = (f32x4){0.f,0.f,0.f,0.f};
#pragma unroll
                for (int h = 0; h < 2; ++h) {
                    st0 = __builtin_amdgcn_mfma_f32_16x16x32_bf16(
                        kf[0][h], qa[s][h], st0, 0, 0, 0);
                    st1 = __builtin_amdgcn_mfma_f32_16x16x32_bf16(
                        kf[1][h], qa[s][h], st1, 0, 0, 0);
                }
                // lane holds keys kh*32 + quad*8 + {0..7} for q = s*16+l16
                float p0 = __builtin_amdgcn_exp2f(st0[0]);
                float p1 = __builtin_amdgcn_exp2f(st0[1]);
                float p2 = __builtin_amdgcn_exp2f(st0[2]);
                float p3 = __builtin_amdgcn_exp2f(st0[3]);
                float p4 = __builtin_amdgcn_exp2f(st1[0]);
                float p5 = __builtin_amdgcn_exp2f(st1[1]);
                float p6 = __builtin_amdgcn_exp2f(st1[2]);
                float p7 = __builtin_amdgcn_exp2f(st1[3]);
                __hip_bfloat162 w0 = __float22bfloat162_rn(make_float2(p0, p1));
                __hip_bfloat162 w1 = __float22bfloat162_rn(make_float2(p2, p3));
                __hip_bfloat162 w2 = __float22bfloat162_rn(make_float2(p4, p5));
                __hip_bfloat162 w3 = __float22bfloat162_rn(make_float2(p6, p7));
                union { bf16x8 v; unsigned int u[4]; } pu;
                pu.u[0] = *reinterpret_cast<unsigned int*>(&w0);
                pu.u[1] = *reinterpret_cast<unsigned int*>(&w1);
                pu.u[2] = *reinterpret_cast<unsigned int*>(&w2);
                pu.u[3] = *reinterpret_cast<unsigned int*>(&w3);
                pf[s] = pu.v;
            }

            // O += P V (pf in-register, vf from the kh>>1 subtile, v13 layout)
#pragma unroll
            for (int dt = 0; dt < 4; ++dt) {
                const int rv2 = dt * 16 + l16;
                const int cvv = ((kh & 1) * 4 + quad) ^ (rv2 & 7);
                bf16x8 vf = *(const bf16x8*)&Vs[ib][kh >> 1][(rv2 * 8 + cvv) * 8];
#pragma unroll
                for (int s = 0; s < 2; ++s)
                    acc[s][dt] = __builtin_amdgcn_mfma_f32_16x16x32_bf16(
                        pf[s], vf, acc[s][dt], 0, 0, 0);
            }
#pragma unroll
            for (int s = 0; s < 2; ++s)
                acc_sum[s] = __builtin_amdgcn_mfma_f32_16x16x32_bf16(
                    pf[s], vones, acc_sum[s], 0, 0, 0);
        }
    }

    // epilogue: denom(q = s*16+quad*4+rr) is in acc_sum[s][rr] of every lane
#pragma unroll
    for (int s = 0; s < 2; ++s)
#pragma unroll
        for (int rr = 0; rr < 4; ++rr) {
            float inv = 1.0f / acc_sum[s][rr];
            int q = qbase + s*16 + quad*4 + rr;
            unsigned short* orow = O + (size_t)(b * SEQ + q) * D_MODEL + head * HEAD_DIM + l16;
#pragma unroll
            for (int dt = 0; dt < 4; ++dt) orow[dt*16] = f2bf(acc[s][dt][rr] * inv);
        }
}

extern "C" void kernel_launch(void* const* d_in, const int* in_sizes, int n_in,
                              void* d_out, int out_size, void* d_ws, size_t ws_size,
                              hipStream_t stream) {
    const float* x    = (const float*)d_in[0];
    const float* wq_c = (const float*)d_in[1];
    const float* wq_b = (const float*)d_in[2];
    const float* wk_c = (const float*)d_in[3];
    const float* wk_b = (const float*)d_in[4];
    const float* wv_c = (const float*)d_in[5];
    const float* wv_b = (const float*)d_in[6];
    const float* wo_c = (const float*)d_in[7];
    const float* wo_b = (const float*)d_in[8];
    float* out = (float*)d_out;

    char* ws = (char*)d_ws;
    unsigned short* Wt   = (unsigned short*)(ws);                        // 8 MB
    float*          bias = (float*)(ws + ((size_t)8  << 20));            // 16 KB
    unsigned short* xb   = (unsigned short*)(ws + ((size_t)10 << 20));   // 16 MB
    unsigned short* Qb   = (unsigned short*)(ws + ((size_t)26 << 20));   // 16 MB
    unsigned short* Kb   = (unsigned short*)(ws + ((size_t)42 << 20));   // 16 MB
    unsigned short* Vt   = (unsigned short*)(ws + ((size_t)58 << 20));   // 16 MB
    unsigned short* Ob   = (unsigned short*)(ws + ((size_t)74 << 20));   // 16 MB

    prep<<<4096 + MROWS, 256, 0, stream>>>(wq_c, wk_c, wv_c, wo_c,
                                           wq_b, wk_b, wv_b, wo_b,
                                           Wt, bias, x, xb);
    gemm_circ<0><<<dim3(64, 24), 256, 0, stream>>>(xb, Wt, bias, Qb, Kb, Vt, nullptr);
    // fast axis = (b,head): round-robin over XCDs; q-tiles (slow) revisit warm L2
    attn_mfma<<<dim3(BATCH * NUM_HEADS, SEQ / 256), 512, 0, stream>>>(Qb, Kb, Vt, Ob);
    gemm_circ<1><<<dim3(64, 8), 256, 0, stream>>>(Ob, Wt + (size_t)3072 * 1024,
                                                  bias + 3072, nullptr, nullptr, nullptr, out);
}